// Round 11
// baseline (136.752 us; speedup 1.0000x reference)
//
#include <hip/hip_runtime.h>
#include <stdint.h>

// DBSCAN-on-voxel-grid, exact port of the JAX reference for batch_size==1.
// Grid 512x512, eps=1.5 => 8-connected adjacency, min_samples=5 (voxels,
// incl. self), clusters with <20 voxels dropped.
// R11 = R10 + WORD-granularity worklists: k_cm appends nonzero-cm words
// (merge list) and nonzero-occ words (cb list); merge/cb run 8 lanes/word
// (4-cell nibble per lane) so the lane group shares context words — fixes
// R9's scattered cell-worklist while cutting 256K-thread grids to ~16K.
// k_vox also caches per-point cell ids for scatter.

#define GRIDW 512
#define WPR 16        // bitmap words per row
#define NWORDS 8192   // 512*512/32
#define NONE 0xFFFFFFFFu

// ---- ws layout (uint32 units) ----
#define OFF_OCC    0       // 8192 (zeroed by memset)
#define OFF_NWM    8192    // 1    (zeroed by memset) count of cm-words
#define OFF_NWO    8193    // 1    (zeroed by memset) count of occ-words
#define FILL_BYTES (8194 * 4)
#define OFF_ROOTBM 8448    // 8192 (zeroed in k_cm)
#define OFF_CM     16640   // 8192
#define OFF_PCELL  24832   // 8192 per-point cell ids
#define OFF_WLM    33024   // 8192 worklist: words with core cells
#define OFF_WLO    41216   // 8192 worklist: words with occupied cells
#define OFF_LAB    49408   // 262144 (occupied entries lazy-init in k_vox)
#define OFF_CNT    311552  // 262144 (occupied entries lazy-zeroed in k_vox)

// per-position horizontal (west+self+east) 2-bit counts for a row of 32 cells
__device__ __forceinline__ void hsum(uint32_t l, uint32_t c, uint32_t r,
                                     uint32_t& h0, uint32_t& h1) {
  uint32_t Wb = (c << 1) | (l >> 31);
  uint32_t Eb = (c >> 1) | (r << 31);
  h0 = Wb ^ c ^ Eb;
  h1 = (Wb & c) | (Eb & (Wb ^ c));
}

// per-position (sum of three 2-bit row counts) >= 5 (bit-sliced adders)
__device__ __forceinline__ uint32_t ge5(uint32_t a0, uint32_t a1, uint32_t b0,
                                        uint32_t b1, uint32_t c0, uint32_t c1) {
  uint32_t u0 = a0 ^ b0, cy = a0 & b0;
  uint32_t t = a1 ^ b1;
  uint32_t u1 = t ^ cy;
  uint32_t u2 = (a1 & b1) | (cy & t);
  uint32_t v0 = u0 ^ c0, k0 = u0 & c0;
  uint32_t t2 = u1 ^ c1;
  uint32_t v1 = t2 ^ k0;
  uint32_t k1 = (u1 & c1) | (k0 & t2);
  uint32_t v2 = u2 ^ k1;
  uint32_t v3 = u2 & k1;
  return v3 | (v2 & (v1 | v0));  // count in {5..9}
}

__device__ __forceinline__ uint32_t aread(uint32_t* p) {
  return __hip_atomic_load(p, __ATOMIC_RELAXED, __HIP_MEMORY_SCOPE_AGENT);
}

// find root with guarded path compression: links only ever DECREASE
// (monotone invariant => no cycles, guaranteed termination).
__device__ __forceinline__ uint32_t findc(uint32_t* L, uint32_t x) {
  uint32_t r = x, p = aread(&L[r]);
  while (p != r) { r = p; p = aread(&L[r]); }
  while (x > r) {
    uint32_t nx = aread(&L[x]);
    if (nx <= r) break;
    atomicCAS(&L[x], nx, r);  // best effort, only writes a smaller value
    x = nx;
  }
  return r;
}

// link larger root under smaller => final root == min core CELL of component
__device__ __forceinline__ void unite(uint32_t* L, uint32_t a, uint32_t b) {
  for (;;) {
    a = findc(L, a);
    b = findc(L, b);
    if (a == b) return;
    uint32_t lo = min(a, b), hi = max(a, b);
    if (atomicCAS(&L[hi], hi, lo) == hi) return;
    a = lo; b = hi;
  }
}

// K1: voxelize; unique setter of each occupancy bit lazy-inits lab/cnt;
// cache per-point cell id for scatter.
__global__ void k_vox(const float* __restrict__ pts, uint32_t* __restrict__ ws,
                      int npts) {
  int i = blockIdx.x * 256 + threadIdx.x;
  if (i >= npts) return;
  float x = pts[i * 5 + 1];
  float y = pts[i * 5 + 2];
  int cx = (int)floorf((x - (-51.2f)) / 0.2f);  // identical f32 ops to jnp
  int cy = (int)floorf((y - (-51.2f)) / 0.2f);
  cx = min(max(cx, 0), GRIDW - 1);
  cy = min(max(cy, 0), GRIDW - 1);
  int cell = cy * GRIDW + cx;
  ws[OFF_PCELL + i] = (uint32_t)cell;
  uint32_t old = atomicOr(&ws[OFF_OCC + (cell >> 5)], 1u << (cell & 31));
  if (!((old >> (cell & 31)) & 1)) {
    ws[OFF_LAB + cell] = (uint32_t)cell;
    ws[OFF_CNT + cell] = 0u;
  }
}

// K2: per-word core mask; zero rootbm; build word worklists
__global__ void k_cm(uint32_t* __restrict__ ws) {
  int wi = blockIdx.x * 256 + threadIdx.x;  // 32 blocks x 256 = 8192 words
  const uint32_t* occ = ws + OFF_OCC;
  ws[OFF_ROOTBM + wi] = 0u;
  uint32_t cB = occ[wi];
  uint32_t cmv = 0u;
  if (cB) {
    int y = wi >> 4, wx = wi & 15;
    uint32_t lB = wx ? occ[wi - 1] : 0u;
    uint32_t rB = (wx < 15) ? occ[wi + 1] : 0u;
    uint32_t cA = 0, lA = 0, rA = 0, cC = 0, lC = 0, rC = 0;
    if (y > 0) { int w = wi - WPR; cA = occ[w]; lA = wx ? occ[w - 1] : 0u; rA = (wx < 15) ? occ[w + 1] : 0u; }
    if (y < GRIDW - 1) { int w = wi + WPR; cC = occ[w]; lC = wx ? occ[w - 1] : 0u; rC = (wx < 15) ? occ[w + 1] : 0u; }
    uint32_t a0, a1, b0, b1, c0, c1;
    hsum(lA, cA, rA, a0, a1); hsum(lB, cB, rB, b0, b1); hsum(lC, cC, rC, c0, c1);
    cmv = ge5(a0, a1, b0, b1, c0, c1) & cB;
    uint32_t io = atomicAdd(&ws[OFF_NWO], 1u);
    ws[OFF_WLO + io] = (uint32_t)wi;
  }
  ws[OFF_CM + wi] = cmv;
  if (cmv) {
    uint32_t im = atomicAdd(&ws[OFF_NWM], 1u);
    ws[OFF_WLM + im] = (uint32_t)wi;
  }
}

// K3: union core-core edges (E, S, SE, SW); 8 lanes/word, 4-cell nibble/lane
__global__ void k_merge(uint32_t* __restrict__ ws) {
  int gid = blockIdx.x * 256 + threadIdx.x;
  int slot = gid >> 3, nib = gid & 7;
  if (slot >= (int)ws[OFF_NWM]) return;
  int wi = (int)ws[OFF_WLM + slot];
  const uint32_t* cm = ws + OFF_CM;
  uint32_t* lab = ws + OFF_LAB;
  uint32_t cw0 = cm[wi];
  uint32_t nmask = (cw0 >> (nib << 2)) & 0xFu;
  if (!nmask) return;
  int wx = wi & 15, y = wi >> 4;
  bool hasS = y < GRIDW - 1;
  uint32_t cmS = hasS ? cm[wi + WPR] : 0u;
  for (int j = 0; j < 4; j++) {
    int b = (nib << 2) + j;
    if (!((cw0 >> b) & 1)) continue;
    int cell = (wi << 5) + b;
    bool eC = (b < 31) ? (((cw0 >> (b + 1)) & 1) != 0)
                       : ((wx < 15) ? ((cm[wi + 1] & 1u) != 0) : false);
    if (eC) unite(lab, cell, cell + 1);
    if (hasS) {
      if ((cmS >> b) & 1) unite(lab, cell, cell + GRIDW);
      bool seC = (b < 31) ? (((cmS >> (b + 1)) & 1) != 0)
                          : ((wx < 15) ? ((cm[wi + WPR + 1] & 1u) != 0) : false);
      if (seC) unite(lab, cell, cell + GRIDW + 1);
      bool swC = (b > 0) ? (((cmS >> (b - 1)) & 1) != 0)
                         : ((wx > 0) ? ((cm[wi + WPR - 1] >> 31) != 0) : false);
      if (swC) unite(lab, cell, cell + GRIDW - 1);
    }
  }
}

// K4: compress (core) / border attach (non-core) + counts; 8 lanes/word
__global__ void k_cb(uint32_t* __restrict__ ws) {
  int gid = blockIdx.x * 256 + threadIdx.x;
  int slot = gid >> 3, nib = gid & 7;
  if (slot >= (int)ws[OFF_NWO]) return;
  int wi = (int)ws[OFF_WLO + slot];
  const uint32_t* cm = ws + OFF_CM;
  uint32_t* lab = ws + OFF_LAB;
  uint32_t* cnt = ws + OFF_CNT;
  uint32_t oB = ws[OFF_OCC + wi];
  uint32_t nmask = (oB >> (nib << 2)) & 0xFu;
  if (!nmask) return;
  uint32_t cw0 = cm[wi];
  int wx = wi & 15, y = wi >> 4;
  bool hasN = y > 0, hasS = y < GRIDW - 1;
  uint32_t cmN = hasN ? cm[wi - WPR] : 0u;
  uint32_t cmS = hasS ? cm[wi + WPR] : 0u;
  for (int j = 0; j < 4; j++) {
    int b = (nib << 2) + j;
    if (!((oB >> b) & 1)) continue;
    int cell = (wi << 5) + b;
    if ((cw0 >> b) & 1) {  // core: compress to final root, mark root, count
      uint32_t root = findc(lab, cell);
      lab[cell] = root;
      if (root == (uint32_t)cell) atomicOr(&ws[OFF_ROOTBM + wi], 1u << b);
      atomicAdd(&cnt[root], 1u);
    } else {               // border: min root among 8 core neighbors
      uint32_t m = NONE;
      bool t;
      t = (b > 0) ? (((cw0 >> (b - 1)) & 1) != 0)
                  : ((wx > 0) ? ((cm[wi - 1] >> 31) != 0) : false);
      if (t) m = min(m, findc(lab, cell - 1));
      t = (b < 31) ? (((cw0 >> (b + 1)) & 1) != 0)
                   : ((wx < 15) ? ((cm[wi + 1] & 1u) != 0) : false);
      if (t) m = min(m, findc(lab, cell + 1));
      if (hasN) {
        if ((cmN >> b) & 1) m = min(m, findc(lab, cell - GRIDW));
        t = (b > 0) ? (((cmN >> (b - 1)) & 1) != 0)
                    : ((wx > 0) ? ((cm[wi - WPR - 1] >> 31) != 0) : false);
        if (t) m = min(m, findc(lab, cell - GRIDW - 1));
        t = (b < 31) ? (((cmN >> (b + 1)) & 1) != 0)
                     : ((wx < 15) ? ((cm[wi - WPR + 1] & 1u) != 0) : false);
        if (t) m = min(m, findc(lab, cell - GRIDW + 1));
      }
      if (hasS) {
        if ((cmS >> b) & 1) m = min(m, findc(lab, cell + GRIDW));
        t = (b > 0) ? (((cmS >> (b - 1)) & 1) != 0)
                    : ((wx > 0) ? ((cm[wi + WPR - 1] >> 31) != 0) : false);
        if (t) m = min(m, findc(lab, cell + GRIDW - 1));
        t = (b < 31) ? (((cmS >> (b + 1)) & 1) != 0)
                     : ((wx < 15) ? ((cm[wi + WPR + 1] & 1u) != 0) : false);
        if (t) m = min(m, findc(lab, cell + GRIDW + 1));
      }
      lab[cell] = m;  // NONE => noise; non-core cells are never UF parents
      if (m != NONE) atomicAdd(&cnt[m], 1u);
    }
  }
}

// K5: fused finish+scatter. Each block builds the dense-root prefix + keep
// bitmap in LDS, then scatters its points via cached pcell.
__global__ __launch_bounds__(256) void k_scatter(
    uint32_t* __restrict__ ws, float* __restrict__ out, int npts) {
  __shared__ uint32_t rpre_s[NWORDS];   // 32 KB
  __shared__ uint32_t keep_s[NWORDS];   // 32 KB
  __shared__ uint32_t wsum[4];
  __shared__ int smax;
  int tid = threadIdx.x;
  if (tid == 0) smax = -1;
  int base = tid * 32;
  uint32_t s = 0;
  for (int j = 0; j < 32; j++) s += __popc(ws[OFF_ROOTBM + base + j]);
  int lane = tid & 63, wv = tid >> 6;
  uint32_t inc = s;
  for (int d = 1; d < 64; d <<= 1) { uint32_t t = __shfl_up(inc, d); if (lane >= d) inc += t; }
  if (lane == 63) wsum[wv] = inc;
  __syncthreads();
  uint32_t woff = 0;
  for (int k = 0; k < wv; k++) woff += wsum[k];
  uint32_t excl = woff + inc - s;
  int mx = -1;
  for (int j = 0; j < 32; j++) {
    uint32_t rbw = ws[OFF_ROOTBM + base + j];
    rpre_s[base + j] = excl;
    uint32_t rb = rbw, keep = 0;
    int d = (int)excl;
    while (rb) {
      int b2 = __ffs(rb) - 1; rb &= rb - 1;
      int r = (base + j) * 32 + b2;
      if (ws[OFF_CNT + r] >= 20u) { keep |= 1u << b2; mx = d; }
      d++;
    }
    keep_s[base + j] = keep;
    excl += __popc(rbw);
  }
  if (mx >= 0) atomicMax(&smax, mx);
  __syncthreads();
  int i = blockIdx.x * 256 + tid;
  if (i < npts) {
    uint32_t cell = ws[OFF_PCELL + i];
    uint32_t l = ws[OFF_LAB + cell];
    float o = -1.0f;
    if (l != NONE && ((keep_s[l >> 5] >> (l & 31)) & 1)) {
      int dnum = rpre_s[l >> 5] +
                 __popc(ws[OFF_ROOTBM + (l >> 5)] & ((1u << (l & 31)) - 1u));
      o = (float)dnum;
    }
    out[i] = o;
  }
  if (tid == 0) out[npts] = (float)(smax + 1);  // same value from every block
}

extern "C" void kernel_launch(void* const* d_in, const int* in_sizes, int n_in,
                              void* d_out, int out_size, void* d_ws, size_t ws_size,
                              hipStream_t stream) {
  const float* pts = (const float*)d_in[0];
  int npts = in_sizes[0] / 5;  // points are (N,5) float32
  uint32_t* ws = (uint32_t*)d_ws;
  float* out = (float*)d_out;
  int pblocks = (npts + 255) / 256;
  hipMemsetAsync(d_ws, 0, FILL_BYTES, stream);  // occ + worklist counters
  k_vox<<<pblocks, 256, 0, stream>>>(pts, ws, npts);
  k_cm<<<NWORDS / 256, 256, 0, stream>>>(ws);
  k_merge<<<NWORDS * 8 / 256, 256, 0, stream>>>(ws);
  k_cb<<<NWORDS * 8 / 256, 256, 0, stream>>>(ws);
  k_scatter<<<pblocks, 256, 0, stream>>>(ws, out, npts);
}